// Round 9
// baseline (224.130 us; speedup 1.0000x reference)
//
#include <hip/hip_runtime.h>
#include <stdint.h>

#define BATCH 32
#define NBOX 8192
#define NGT 128
#define M (NBOX + NGT)     // 8320
#define K_OUT 512
#define MAX_FG 128
#define C_CAP 256
#define S_CAP 256
#define U_CAP 1024
#define CAND_MAGIC 0xFFFFu

// Monotone clamped bucket for select: order-preserving coarsening of noise.
__device__ __forceinline__ unsigned int bkt1024(float ns) {
    unsigned int u = (unsigned int)(ns * 16777216.0f) >> 14;
    return u > 1023u ? 1023u : u;
}

// ---------------------------------------------------------------------------
// Pass 1 (R9): branch-free candidate classification. Per pair only
//   acc = fmaxf(acc, ia - 0.5*den)   [exact: cand <=> exact q > 0.5]
// ~15 VALU insts/pair, zero decision state in the loop (R6 counters showed
// the old tracking loop compiled to ~69 insts/pair). gt[g] is wave-uniform ->
// s_load (scalar cache). Rows with acc>0 are a tight superset of pos (RN
// monotone); they get CAND_MAGIC and are finalized exactly in pass 2.
// ---------------------------------------------------------------------------
__global__ __launch_bounds__(256) void iou_kernel(
    const float* __restrict__ boxes,      // [B, NBOX, 4]
    const float* __restrict__ gt_boxes,   // [B, NGT, 4]
    unsigned short* __restrict__ packed)  // [B, M]
{
    const int BPB = (M + 255) / 256;      // 33
    const int b = blockIdx.x / BPB;
    const int m = (blockIdx.x % BPB) * 256 + threadIdx.x;
    if (m >= M) return;

    const float4* __restrict__ gt = ((const float4*)gt_boxes) + b * NGT;

    float4 bb = (m < NBOX) ? ((const float4*)boxes)[b * NBOX + m]
                           : gt[m - NBOX];
    const float barea = __fmul_rn(__fsub_rn(bb.z, bb.x), __fsub_rn(bb.w, bb.y));

    float acc = -1.0f;
    #pragma unroll 4
    for (int g = 0; g < NGT; ++g) {
        float4 gg = gt[g];                 // uniform -> s_load_dwordx4
        float ga = __fmul_rn(__fsub_rn(gg.z, gg.x), __fsub_rn(gg.w, gg.y));
        float dy = __fsub_rn(fminf(bb.z, gg.z), fmaxf(bb.x, gg.x));
        float dx = __fsub_rn(fminf(bb.w, gg.w), fmaxf(bb.y, gg.y));
        float ia = __fmul_rn(fmaxf(dy, 0.f), fmaxf(dx, 0.f));
        float den = __fsub_rn(__fadd_rn(barea, ga), ia);
        acc = fmaxf(acc, __fsub_rn(ia, __fmul_rn(0.5f, den)));
    }
    packed[b * M + m] = (acc > 0.f) ? (unsigned short)CAND_MAGIC
                                    : (unsigned short)256;
}

// ---------------------------------------------------------------------------
// Pass 2 (R9): exact finalize of flagged rows (~4%). One wave per flagged
// row, reference semantics verbatim: q_g = __fdiv_rn per g, first-max argmax
// (lane pair g/g+64, strict > keeps lower g; shfl-xor reduce with index
// tiebreak), pos = rounded max > 0.5. Strips of 64 rows scanned by ballot.
// ---------------------------------------------------------------------------
__global__ __launch_bounds__(256) void argmax_kernel(
    const float* __restrict__ boxes,
    const float* __restrict__ gt_boxes,
    unsigned short* __restrict__ packed)
{
    const int lane = threadIdx.x & 63;
    const int gw = blockIdx.x * 4 + (threadIdx.x >> 6);   // global wave id
    const int NSTRIP = BATCH * (M / 64);                  // 4160

    for (int strip = gw; strip < NSTRIP; strip += gridDim.x * 4) {
        const int b = strip / (M / 64);
        const int row0 = (strip % (M / 64)) * 64;
        const float4* __restrict__ gt = ((const float4*)gt_boxes) + b * NGT;

        unsigned short pk = packed[(size_t)b * M + row0 + lane];
        unsigned long long mask = __ballot(pk == CAND_MAGIC);
        while (mask) {
            int bit = __ffsll((long long)mask) - 1; mask &= mask - 1;
            int row = row0 + bit;
            float4 bb = (row < NBOX) ? ((const float4*)boxes)[b * NBOX + row]
                                     : gt[row - NBOX];
            float barea = __fmul_rn(__fsub_rn(bb.z, bb.x), __fsub_rn(bb.w, bb.y));

            int g0 = lane, g1 = lane + 64;
            float q0, q1;
            {
                float4 gg = gt[g0];
                float ga = __fmul_rn(__fsub_rn(gg.z, gg.x), __fsub_rn(gg.w, gg.y));
                float dy = __fsub_rn(fminf(bb.z, gg.z), fmaxf(bb.x, gg.x));
                float dx = __fsub_rn(fminf(bb.w, gg.w), fmaxf(bb.y, gg.y));
                float ia = __fmul_rn(fmaxf(dy, 0.f), fmaxf(dx, 0.f));
                float den = __fsub_rn(__fadd_rn(barea, ga), ia);
                q0 = __fdiv_rn(ia, den);
            }
            {
                float4 gg = gt[g1];
                float ga = __fmul_rn(__fsub_rn(gg.z, gg.x), __fsub_rn(gg.w, gg.y));
                float dy = __fsub_rn(fminf(bb.z, gg.z), fmaxf(bb.x, gg.x));
                float dx = __fsub_rn(fminf(bb.w, gg.w), fmaxf(bb.y, gg.y));
                float ia = __fmul_rn(fmaxf(dy, 0.f), fmaxf(dx, 0.f));
                float den = __fsub_rn(__fadd_rn(barea, ga), ia);
                q1 = __fdiv_rn(ia, den);
            }
            float qv = q0; int qi = g0;
            if (q1 > q0) { qv = q1; qi = g1; }     // strict >: lower g on tie
            #pragma unroll
            for (int off = 1; off < 64; off <<= 1) {
                float ov = __shfl_xor(qv, off, 64);
                int   oi = __shfl_xor(qi, off, 64);
                if (ov > qv || (ov == qv && oi < qi)) { qv = ov; qi = oi; }
            }
            if (lane == 0)
                packed[(size_t)b * M + row] =
                    (qv > 0.5f) ? (unsigned short)(qi | 512) : (unsigned short)256;
        }
    }
}

// ---------------------------------------------------------------------------
// Kernel 3 (byte-identical to R5/R6/R7/R8 — verified absmax 0.0 four times).
// ---------------------------------------------------------------------------
__global__ __launch_bounds__(1024) void select_kernel(
    const float* __restrict__ boxes,
    const float* __restrict__ gt_boxes,
    const int*   __restrict__ gt_labels,
    const float* __restrict__ noise,      // [B, M]
    const unsigned short* __restrict__ packed,
    float* __restrict__ out)
{
    const int b = blockIdx.x;
    const int tid = threadIdx.x;

    __shared__ float sh_ns[M];
    __shared__ unsigned int hist[1024];
    __shared__ unsigned int hist2[1024];
    __shared__ unsigned char posmask[M / 8];
    __shared__ unsigned char negmask[M / 8];
    __shared__ float4 sgt[NGT];
    __shared__ int slab[NGT];
    __shared__ float C[C_CAP];
    __shared__ unsigned short slist[S_CAP];
    __shared__ unsigned int ukey[U_CAP];
    __shared__ unsigned short um[U_CAP];
    __shared__ unsigned int sh_Bp, sh_needp, sh_cc, sh_n1a, sh_B, sh_cnt, sh_kth;

    float* out_bt  = out;
    float* out_cls = out + BATCH * K_OUT * 4;
    float* out_roi = out + BATCH * K_OUT * 5;
    float* out_p2l = out + BATCH * K_OUT * 9;

    hist[tid] = 0;
    hist2[tid] = 0;
    if (tid == 0) { sh_cc = 0; sh_n1a = 0; sh_B = 0; sh_cnt = 0; sh_kth = 0xBF800000u; }
    if (tid < NGT) {
        sgt[tid]  = ((const float4*)gt_boxes)[b * NGT + tid];
        slab[tid] = gt_labels[b * NGT + tid];
    }
    __syncthreads();

    {
        const uint4*  pk4 = (const uint4*)(packed + (size_t)b * M);
        const float4* ns4 = (const float4*)(noise + (size_t)b * M);
        for (int c = tid; c < M / 8; c += 1024) {
            uint4 pv = pk4[c];
            float4 n0 = ns4[2 * c], n1v = ns4[2 * c + 1];
            ((float4*)sh_ns)[2 * c] = n0;
            ((float4*)sh_ns)[2 * c + 1] = n1v;
            unsigned short e[8];
            e[0] = (unsigned short)(pv.x & 0xFFFF); e[1] = (unsigned short)(pv.x >> 16);
            e[2] = (unsigned short)(pv.y & 0xFFFF); e[3] = (unsigned short)(pv.y >> 16);
            e[4] = (unsigned short)(pv.z & 0xFFFF); e[5] = (unsigned short)(pv.z >> 16);
            e[6] = (unsigned short)(pv.w & 0xFFFF); e[7] = (unsigned short)(pv.w >> 16);
            float f[8] = {n0.x, n0.y, n0.z, n0.w, n1v.x, n1v.y, n1v.z, n1v.w};
            unsigned int pb = 0, nb = 0;
            #pragma unroll
            for (int k = 0; k < 8; ++k) {
                if (e[k] & 512) {
                    pb |= (1u << k);
                    atomicAdd(&hist2[bkt1024(f[k])], 1u);
                } else if (e[k] & 256) {
                    nb |= (1u << k);
                    atomicAdd(&hist[bkt1024(f[k])], 1u);
                }
            }
            posmask[c] = (unsigned char)pb;
            negmask[c] = (unsigned char)nb;
        }
    }
    __syncthreads();

    {
        const int wv = tid >> 6, ln = tid & 63;
        if (wv < 2) {
            unsigned int* H = wv ? hist2 : hist;
            unsigned int s[16];
            #pragma unroll
            for (int k = 0; k < 16; ++k) {
                unsigned int v = H[k * 64 + ln];
                #pragma unroll
                for (int off = 1; off < 64; off <<= 1) {
                    unsigned int o = __shfl_down(v, off, 64);
                    if (ln + off < 64) v += o;
                }
                s[k] = v;
            }
            unsigned int after = 0;
            #pragma unroll
            for (int k = 15; k >= 0; --k) {
                unsigned int tot = __shfl(s[k], 0, 64);
                H[k * 64 + ln] = s[k] + after;
                after += tot;
            }
        }
    }
    __syncthreads();
    const unsigned int nneg = hist[0];
    const unsigned int npos = hist2[0];

    if (npos >= MAX_FG) {
        {
            unsigned int S  = hist2[tid];
            unsigned int Sn = (tid < 1023) ? hist2[tid + 1] : 0;
            if (S >= MAX_FG && Sn < MAX_FG) { sh_Bp = tid; sh_needp = MAX_FG - Sn; }
        }
        __syncthreads();
        const unsigned int Bp = sh_Bp, needp = sh_needp;
        for (int c = tid; c < M / 8; c += 1024) {
            unsigned int pb = posmask[c];
            while (pb) {
                int k = __ffs(pb) - 1; pb &= pb - 1;
                float v = sh_ns[c * 8 + k];
                if (bkt1024(v) == Bp) {
                    unsigned int slot = atomicAdd(&sh_cc, 1u);
                    if (slot < C_CAP) C[slot] = v;
                }
            }
        }
        __syncthreads();
        {
            unsigned int cc = min(sh_cc, (unsigned int)C_CAP);
            if (tid < (int)cc) {
                float my = C[tid];
                unsigned int g = 0, e = 0;
                for (unsigned int j = 0; j < cc; ++j) {
                    float v = C[j];
                    g += (v > my) ? 1u : 0u;
                    e += (v == my) ? 1u : 0u;
                }
                if (g < needp && g + e >= needp) sh_kth = __float_as_uint(my);
            }
        }
        __syncthreads();
    }
    const float kthf = __uint_as_float(sh_kth);

    for (int c = tid; c < M / 8; c += 1024) {
        unsigned int pb = posmask[c];
        while (pb) {
            int k = __ffs(pb) - 1; pb &= pb - 1;
            int m = c * 8 + k;
            if (sh_ns[m] >= kthf) {
                unsigned int slot = atomicAdd(&sh_n1a, 1u);
                if (slot < S_CAP) slist[slot] = (unsigned short)m;
            }
        }
    }
    __syncthreads();
    const unsigned int n1 = min(sh_n1a, (unsigned int)S_CAP);
    const unsigned int k2 = K_OUT - n1;
    const bool enough_neg = (nneg >= k2);

    if (enough_neg) {
        unsigned int S  = hist[tid];
        unsigned int Sn = (tid < 1023) ? hist[tid + 1] : 0;
        if (S >= k2 && Sn < k2) sh_B = tid;
    }
    if (tid < (int)n1) {
        int mi = slist[tid];
        float nsi = sh_ns[mi];
        float ci = __fadd_rn(2.0f, nsi);
        unsigned int r = 0;
        for (unsigned int j = 0; j < n1; ++j) {
            int mj = slist[j];
            float cj = __fadd_rn(2.0f, sh_ns[mj]);
            if (cj > ci || (cj == ci && mj < mi)) ++r;
        }
        int pkv = packed[(size_t)b * M + mi];
        int lbl = pkv & 127;
        float4 roi = (mi < NBOX) ? ((const float4*)boxes)[b * NBOX + mi]
                                 : sgt[mi - NBOX];
        ((float4*)out_bt)[b * K_OUT + r] = sgt[lbl];
        out_cls[b * K_OUT + r] = (float)slab[lbl];
        ((float4*)out_roi)[b * K_OUT + r] = roi;
        out_p2l[b * K_OUT + r] = (float)lbl;
    }
    __syncthreads();
    const unsigned int B1 = sh_B;

    for (int c = tid; c < M / 8; c += 1024) {
        unsigned int nb = negmask[c];
        while (nb) {
            int k = __ffs(nb) - 1; nb &= nb - 1;
            int m = c * 8 + k;
            float v = sh_ns[m];
            if (bkt1024(v) >= B1) {
                unsigned int slot = atomicAdd(&sh_cnt, 1u);
                if (slot < U_CAP) {
                    ukey[slot] = __float_as_uint(v);
                    um[slot]   = (unsigned short)m;
                }
            }
        }
    }
    __syncthreads();

    const unsigned int q = min(sh_cnt, (unsigned int)U_CAP);
    for (unsigned int i = tid; i < q; i += 1024) {
        unsigned int ki = ukey[i];
        unsigned short mi = um[i];
        unsigned int r = 0;
        for (unsigned int j = 0; j < q; ++j) {
            unsigned int kj = ukey[j];
            if (kj > ki || (kj == ki && um[j] < mi)) ++r;
        }
        if (r < k2) {
            float4 roi = (mi < NBOX) ? ((const float4*)boxes)[b * NBOX + mi]
                                     : sgt[mi - NBOX];
            unsigned int gr = n1 + r;
            ((float4*)out_bt)[b * K_OUT + gr] = make_float4(0.f, 0.f, 0.f, 0.f);
            out_cls[b * K_OUT + gr] = 0.0f;
            ((float4*)out_roi)[b * K_OUT + gr] = roi;
            out_p2l[b * K_OUT + gr] = 0.0f;
        }
    }

    if (!enough_neg) {
        __syncthreads();
        const unsigned int k3 = k2 - nneg;
        for (int m = tid; m < M; m += 1024) {
            if (((posmask[m >> 3] >> (m & 7)) & 1) && sh_ns[m] < kthf) {
                unsigned int r = 0;
                for (int m2 = 0; m2 < m; ++m2)
                    if (((posmask[m2 >> 3] >> (m2 & 7)) & 1) && sh_ns[m2] < kthf) ++r;
                if (r < k3) {
                    int pkv = packed[(size_t)b * M + m];
                    int lbl = pkv & 127;
                    float4 roi = (m < NBOX) ? ((const float4*)boxes)[b * NBOX + m]
                                            : sgt[m - NBOX];
                    unsigned int gr = n1 + nneg + r;
                    ((float4*)out_bt)[b * K_OUT + gr] = sgt[lbl];
                    out_cls[b * K_OUT + gr] = (float)slab[lbl];
                    ((float4*)out_roi)[b * K_OUT + gr] = roi;
                    out_p2l[b * K_OUT + gr] = (float)lbl;
                }
            }
        }
    }
}

extern "C" void kernel_launch(void* const* d_in, const int* in_sizes, int n_in,
                              void* d_out, int out_size, void* d_ws, size_t ws_size,
                              hipStream_t stream) {
    const float* boxes     = (const float*)d_in[0];
    const float* gt_boxes  = (const float*)d_in[1];
    const int*   gt_labels = (const int*)d_in[2];
    const float* noise     = (const float*)d_in[3];
    unsigned short* packed = (unsigned short*)d_ws;   // B*M u16 = 532,480 B
    float* out = (float*)d_out;

    const int BPB = (M + 255) / 256;   // 33
    iou_kernel<<<BATCH * BPB, 256, 0, stream>>>(boxes, gt_boxes, packed);
    argmax_kernel<<<520, 256, 0, stream>>>(boxes, gt_boxes, packed);
    select_kernel<<<BATCH, 1024, 0, stream>>>(boxes, gt_boxes, gt_labels, noise,
                                              packed, out);
}

// Round 10
// 122.650 us; speedup vs baseline: 1.8274x; 1.8274x over previous
//
#include <hip/hip_runtime.h>
#include <stdint.h>

#define BATCH 32
#define NBOX 8192
#define NGT 128
#define M (NBOX + NGT)     // 8320
#define K_OUT 512
#define MAX_FG 128
#define C_CAP 256
#define S_CAP 256
#define U_CAP 1024

// Monotone clamped bucket for select: order-preserving coarsening of noise.
__device__ __forceinline__ unsigned int bkt1024(float ns) {
    unsigned int u = (unsigned int)(ns * 16777216.0f) >> 14;
    return u > 1023u ? 1023u : u;
}

// ---------------------------------------------------------------------------
// Kernel 1 (R10): split-g occupancy kernel. 512 thr/block: waves 0-3 handle
// 256 rows x g in [0,64), waves 4-7 same rows x g in [64,128). 1056 blocks
// -> 8448 waves = 8.2/SIMD (2x the 4160-row-wave ceiling that latency-bound
// all prior variants at ~37us). Branch-free loop: q ~= ia * v_rcp(den),
// track (best, sec, argmax) with min/max/cndmask. Halves combine via LDS.
// Epilogue: gap > best*2^-20 (2.3x the rcp+round mis-order window) -> ONE
// exact __fdiv_rn on the winner = reference's rounded max (gap > 2^-24 so
// no earlier g can round equal); else rare exact rescan (divs gated to
// contenders, first-max semantics verbatim).
// ---------------------------------------------------------------------------
__global__ __launch_bounds__(512, 8) void iou_kernel(
    const float* __restrict__ boxes,      // [B, NBOX, 4]
    const float* __restrict__ gt_boxes,   // [B, NGT, 4]
    unsigned short* __restrict__ packed)  // [B, M]
{
    const int BPB = 33;                   // 33 blocks/batch x 256 rows
    const int b = blockIdx.x / BPB;
    const int rloc = threadIdx.x & 255;
    const int half = threadIdx.x >> 8;    // wave-uniform (waves 0-3 vs 4-7)
    const int row = (blockIdx.x % BPB) * 256 + rloc;
    const bool valid = row < M;

    const float4* __restrict__ gt = ((const float4*)gt_boxes) + b * NGT;

    float4 bb = make_float4(0.f, 0.f, 0.f, 0.f);
    if (valid) bb = (row < NBOX) ? ((const float4*)boxes)[b * NBOX + row]
                                 : gt[row - NBOX];
    const float barea = __fmul_rn(__fsub_rn(bb.z, bb.x), __fsub_rn(bb.w, bb.y));

    const float4* __restrict__ gtH = gt + half * 64;
    float best = 0.f, sec = 0.f;
    int bi = half * 64;

    #pragma unroll 8
    for (int j = 0; j < 64; ++j) {
        float4 gg = gtH[j];               // wave-uniform -> s_load_dwordx4
        float ga = __fmul_rn(__fsub_rn(gg.z, gg.x), __fsub_rn(gg.w, gg.y));
        float dy = __fsub_rn(fminf(bb.z, gg.z), fmaxf(bb.x, gg.x));
        float dx = __fsub_rn(fminf(bb.w, gg.w), fmaxf(bb.y, gg.y));
        float ia = __fmul_rn(fmaxf(dy, 0.f), fmaxf(dx, 0.f));
        float den = __fsub_rn(__fadd_rn(barea, ga), ia);
        float q = __fmul_rn(ia, __builtin_amdgcn_rcpf(den));
        float minb = fminf(best, q);
        sec = fmaxf(sec, minb);
        bool tk = q > best;               // strict: first-max kept
        best = fmaxf(best, q);
        bi = tk ? (half * 64 + j) : bi;
    }

    __shared__ float Lb[256];
    __shared__ float Ls[256];
    __shared__ int   Li[256];
    if (half == 1) { Lb[rloc] = best; Ls[rloc] = sec; Li[rloc] = bi; }
    __syncthreads();
    if (half == 1) return;

    if (!valid) return;
    {
        float bB = Lb[rloc], sB = Ls[rloc];
        int   iB = Li[rloc];
        float minb = fminf(best, bB);
        float secAll = fmaxf(minb, fmaxf(sec, sB));
        bool takeB = bB > best;           // equal -> half0 (lower g) wins
        float bAll = takeB ? bB : best;
        int   iAll = takeB ? iB : bi;

        unsigned short pk;
        if (bAll <= 0.f) {
            pk = (unsigned short)256;     // all exact q == 0 -> neg
        } else {
            bool flag = __fsub_rn(bAll, secAll) <=
                        __fmul_rn(bAll, 9.5367431640625e-7f);   // 2^-20
            int bidx; float q;
            if (!flag) {
                bidx = iAll;
                float4 gg = gt[bidx];     // per-lane index -> vmem gather
                float ga = __fmul_rn(__fsub_rn(gg.z, gg.x), __fsub_rn(gg.w, gg.y));
                float dy = __fsub_rn(fminf(bb.z, gg.z), fmaxf(bb.x, gg.x));
                float dx = __fsub_rn(fminf(bb.w, gg.w), fmaxf(bb.y, gg.y));
                float ia = __fmul_rn(fmaxf(dy, 0.f), fmaxf(dx, 0.f));
                float den = __fsub_rn(__fadd_rn(barea, ga), ia);
                q = __fdiv_rn(ia, den);   // rounded max == ref max_ov
            } else {
                // exact rescan, reference verbatim; divs gated to contenders
                float bq = -1e30f; bidx = 0;
                for (int g = 0; g < NGT; ++g) {
                    float4 gg = gt[g];
                    float ga = __fmul_rn(__fsub_rn(gg.z, gg.x), __fsub_rn(gg.w, gg.y));
                    float dy = __fsub_rn(fminf(bb.z, gg.z), fmaxf(bb.x, gg.x));
                    float dx = __fsub_rn(fminf(bb.w, gg.w), fmaxf(bb.y, gg.y));
                    float ia = __fmul_rn(fmaxf(dy, 0.f), fmaxf(dx, 0.f));
                    float den = __fsub_rn(__fadd_rn(barea, ga), ia);
                    float qa = __fmul_rn(ia, __builtin_amdgcn_rcpf(den));
                    // any g with exact q >= current exact max satisfies this
                    if (qa > __fsub_rn(bq, __fmul_rn(fabsf(bq), 9.5367431640625e-7f))) {
                        float qe = __fdiv_rn(ia, den);
                        if (qe > bq) { bq = qe; bidx = g; }   // first-max
                    }
                }
                q = bq;
            }
            bool pos = q > 0.5f;          // exact rounded compare
            pk = (unsigned short)(pos ? (bidx | 512) : 256);
        }
        packed[(size_t)b * M + row] = pk;
    }
}

// ---------------------------------------------------------------------------
// Kernel 2 (byte-identical to R5-R9 — verified absmax 0.0 five times).
// ---------------------------------------------------------------------------
__global__ __launch_bounds__(1024) void select_kernel(
    const float* __restrict__ boxes,
    const float* __restrict__ gt_boxes,
    const int*   __restrict__ gt_labels,
    const float* __restrict__ noise,      // [B, M]
    const unsigned short* __restrict__ packed,
    float* __restrict__ out)
{
    const int b = blockIdx.x;
    const int tid = threadIdx.x;

    __shared__ float sh_ns[M];
    __shared__ unsigned int hist[1024];
    __shared__ unsigned int hist2[1024];
    __shared__ unsigned char posmask[M / 8];
    __shared__ unsigned char negmask[M / 8];
    __shared__ float4 sgt[NGT];
    __shared__ int slab[NGT];
    __shared__ float C[C_CAP];
    __shared__ unsigned short slist[S_CAP];
    __shared__ unsigned int ukey[U_CAP];
    __shared__ unsigned short um[U_CAP];
    __shared__ unsigned int sh_Bp, sh_needp, sh_cc, sh_n1a, sh_B, sh_cnt, sh_kth;

    float* out_bt  = out;
    float* out_cls = out + BATCH * K_OUT * 4;
    float* out_roi = out + BATCH * K_OUT * 5;
    float* out_p2l = out + BATCH * K_OUT * 9;

    hist[tid] = 0;
    hist2[tid] = 0;
    if (tid == 0) { sh_cc = 0; sh_n1a = 0; sh_B = 0; sh_cnt = 0; sh_kth = 0xBF800000u; }
    if (tid < NGT) {
        sgt[tid]  = ((const float4*)gt_boxes)[b * NGT + tid];
        slab[tid] = gt_labels[b * NGT + tid];
    }
    __syncthreads();

    {
        const uint4*  pk4 = (const uint4*)(packed + (size_t)b * M);
        const float4* ns4 = (const float4*)(noise + (size_t)b * M);
        for (int c = tid; c < M / 8; c += 1024) {
            uint4 pv = pk4[c];
            float4 n0 = ns4[2 * c], n1v = ns4[2 * c + 1];
            ((float4*)sh_ns)[2 * c] = n0;
            ((float4*)sh_ns)[2 * c + 1] = n1v;
            unsigned short e[8];
            e[0] = (unsigned short)(pv.x & 0xFFFF); e[1] = (unsigned short)(pv.x >> 16);
            e[2] = (unsigned short)(pv.y & 0xFFFF); e[3] = (unsigned short)(pv.y >> 16);
            e[4] = (unsigned short)(pv.z & 0xFFFF); e[5] = (unsigned short)(pv.z >> 16);
            e[6] = (unsigned short)(pv.w & 0xFFFF); e[7] = (unsigned short)(pv.w >> 16);
            float f[8] = {n0.x, n0.y, n0.z, n0.w, n1v.x, n1v.y, n1v.z, n1v.w};
            unsigned int pb = 0, nb = 0;
            #pragma unroll
            for (int k = 0; k < 8; ++k) {
                if (e[k] & 512) {
                    pb |= (1u << k);
                    atomicAdd(&hist2[bkt1024(f[k])], 1u);
                } else if (e[k] & 256) {
                    nb |= (1u << k);
                    atomicAdd(&hist[bkt1024(f[k])], 1u);
                }
            }
            posmask[c] = (unsigned char)pb;
            negmask[c] = (unsigned char)nb;
        }
    }
    __syncthreads();

    {
        const int wv = tid >> 6, ln = tid & 63;
        if (wv < 2) {
            unsigned int* H = wv ? hist2 : hist;
            unsigned int s[16];
            #pragma unroll
            for (int k = 0; k < 16; ++k) {
                unsigned int v = H[k * 64 + ln];
                #pragma unroll
                for (int off = 1; off < 64; off <<= 1) {
                    unsigned int o = __shfl_down(v, off, 64);
                    if (ln + off < 64) v += o;
                }
                s[k] = v;
            }
            unsigned int after = 0;
            #pragma unroll
            for (int k = 15; k >= 0; --k) {
                unsigned int tot = __shfl(s[k], 0, 64);
                H[k * 64 + ln] = s[k] + after;
                after += tot;
            }
        }
    }
    __syncthreads();
    const unsigned int nneg = hist[0];
    const unsigned int npos = hist2[0];

    if (npos >= MAX_FG) {
        {
            unsigned int S  = hist2[tid];
            unsigned int Sn = (tid < 1023) ? hist2[tid + 1] : 0;
            if (S >= MAX_FG && Sn < MAX_FG) { sh_Bp = tid; sh_needp = MAX_FG - Sn; }
        }
        __syncthreads();
        const unsigned int Bp = sh_Bp, needp = sh_needp;
        for (int c = tid; c < M / 8; c += 1024) {
            unsigned int pb = posmask[c];
            while (pb) {
                int k = __ffs(pb) - 1; pb &= pb - 1;
                float v = sh_ns[c * 8 + k];
                if (bkt1024(v) == Bp) {
                    unsigned int slot = atomicAdd(&sh_cc, 1u);
                    if (slot < C_CAP) C[slot] = v;
                }
            }
        }
        __syncthreads();
        {
            unsigned int cc = min(sh_cc, (unsigned int)C_CAP);
            if (tid < (int)cc) {
                float my = C[tid];
                unsigned int g = 0, e = 0;
                for (unsigned int j = 0; j < cc; ++j) {
                    float v = C[j];
                    g += (v > my) ? 1u : 0u;
                    e += (v == my) ? 1u : 0u;
                }
                if (g < needp && g + e >= needp) sh_kth = __float_as_uint(my);
            }
        }
        __syncthreads();
    }
    const float kthf = __uint_as_float(sh_kth);

    for (int c = tid; c < M / 8; c += 1024) {
        unsigned int pb = posmask[c];
        while (pb) {
            int k = __ffs(pb) - 1; pb &= pb - 1;
            int m = c * 8 + k;
            if (sh_ns[m] >= kthf) {
                unsigned int slot = atomicAdd(&sh_n1a, 1u);
                if (slot < S_CAP) slist[slot] = (unsigned short)m;
            }
        }
    }
    __syncthreads();
    const unsigned int n1 = min(sh_n1a, (unsigned int)S_CAP);
    const unsigned int k2 = K_OUT - n1;
    const bool enough_neg = (nneg >= k2);

    if (enough_neg) {
        unsigned int S  = hist[tid];
        unsigned int Sn = (tid < 1023) ? hist[tid + 1] : 0;
        if (S >= k2 && Sn < k2) sh_B = tid;
    }
    if (tid < (int)n1) {
        int mi = slist[tid];
        float nsi = sh_ns[mi];
        float ci = __fadd_rn(2.0f, nsi);
        unsigned int r = 0;
        for (unsigned int j = 0; j < n1; ++j) {
            int mj = slist[j];
            float cj = __fadd_rn(2.0f, sh_ns[mj]);
            if (cj > ci || (cj == ci && mj < mi)) ++r;
        }
        int pkv = packed[(size_t)b * M + mi];
        int lbl = pkv & 127;
        float4 roi = (mi < NBOX) ? ((const float4*)boxes)[b * NBOX + mi]
                                 : sgt[mi - NBOX];
        ((float4*)out_bt)[b * K_OUT + r] = sgt[lbl];
        out_cls[b * K_OUT + r] = (float)slab[lbl];
        ((float4*)out_roi)[b * K_OUT + r] = roi;
        out_p2l[b * K_OUT + r] = (float)lbl;
    }
    __syncthreads();
    const unsigned int B1 = sh_B;

    for (int c = tid; c < M / 8; c += 1024) {
        unsigned int nb = negmask[c];
        while (nb) {
            int k = __ffs(nb) - 1; nb &= nb - 1;
            int m = c * 8 + k;
            float v = sh_ns[m];
            if (bkt1024(v) >= B1) {
                unsigned int slot = atomicAdd(&sh_cnt, 1u);
                if (slot < U_CAP) {
                    ukey[slot] = __float_as_uint(v);
                    um[slot]   = (unsigned short)m;
                }
            }
        }
    }
    __syncthreads();

    const unsigned int q = min(sh_cnt, (unsigned int)U_CAP);
    for (unsigned int i = tid; i < q; i += 1024) {
        unsigned int ki = ukey[i];
        unsigned short mi = um[i];
        unsigned int r = 0;
        for (unsigned int j = 0; j < q; ++j) {
            unsigned int kj = ukey[j];
            if (kj > ki || (kj == ki && um[j] < mi)) ++r;
        }
        if (r < k2) {
            float4 roi = (mi < NBOX) ? ((const float4*)boxes)[b * NBOX + mi]
                                     : sgt[mi - NBOX];
            unsigned int gr = n1 + r;
            ((float4*)out_bt)[b * K_OUT + gr] = make_float4(0.f, 0.f, 0.f, 0.f);
            out_cls[b * K_OUT + gr] = 0.0f;
            ((float4*)out_roi)[b * K_OUT + gr] = roi;
            out_p2l[b * K_OUT + gr] = 0.0f;
        }
    }

    if (!enough_neg) {
        __syncthreads();
        const unsigned int k3 = k2 - nneg;
        for (int m = tid; m < M; m += 1024) {
            if (((posmask[m >> 3] >> (m & 7)) & 1) && sh_ns[m] < kthf) {
                unsigned int r = 0;
                for (int m2 = 0; m2 < m; ++m2)
                    if (((posmask[m2 >> 3] >> (m2 & 7)) & 1) && sh_ns[m2] < kthf) ++r;
                if (r < k3) {
                    int pkv = packed[(size_t)b * M + m];
                    int lbl = pkv & 127;
                    float4 roi = (m < NBOX) ? ((const float4*)boxes)[b * NBOX + m]
                                            : sgt[m - NBOX];
                    unsigned int gr = n1 + nneg + r;
                    ((float4*)out_bt)[b * K_OUT + gr] = sgt[lbl];
                    out_cls[b * K_OUT + gr] = (float)slab[lbl];
                    ((float4*)out_roi)[b * K_OUT + gr] = roi;
                    out_p2l[b * K_OUT + gr] = (float)lbl;
                }
            }
        }
    }
}

extern "C" void kernel_launch(void* const* d_in, const int* in_sizes, int n_in,
                              void* d_out, int out_size, void* d_ws, size_t ws_size,
                              hipStream_t stream) {
    const float* boxes     = (const float*)d_in[0];
    const float* gt_boxes  = (const float*)d_in[1];
    const int*   gt_labels = (const int*)d_in[2];
    const float* noise     = (const float*)d_in[3];
    unsigned short* packed = (unsigned short*)d_ws;   // B*M u16 = 532,480 B
    float* out = (float*)d_out;

    iou_kernel<<<BATCH * 33, 512, 0, stream>>>(boxes, gt_boxes, packed);
    select_kernel<<<BATCH, 1024, 0, stream>>>(boxes, gt_boxes, gt_labels, noise,
                                              packed, out);
}